// Round 2
// baseline (122.157 us; speedup 1.0000x reference)
//
#include <hip/hip_runtime.h>

// Problem dims (fixed by reference): bs=4, L=512, H=768, C=48
#define H_DIM 768
#define C_DIM 48
#define NROWS 2048          // bs * L
#define TWO_H 1536

// ---------------------------------------------------------------------------
// Kernel 1: proj[half][row][ci] = dot(hs[row,:], W[ci, half*768 + :])
// grid = (12, 32), block = 64 (one wave).
//   wave handles 8 consecutive c = bx*8 .. bx*8+7   (0..95)
//   lane handles row = by*64 + lane                 (0..2047)
// hs float4 load is scattered (lane-varying row) but each load is reused for
// 8 columns; W rows are wave-uniform -> scalar (s_load) via readfirstlane.
// c0 is a multiple of 8 so a wave's 8 columns never cross the half=48 split.
// ---------------------------------------------------------------------------
__global__ __launch_bounds__(64) void proj_kernel(const float* __restrict__ hs,
                                                  const float* __restrict__ W,
                                                  float* __restrict__ proj) {
    const int lane = threadIdx.x;
    const int c0   = __builtin_amdgcn_readfirstlane((int)blockIdx.x * 8);
    const int row  = (int)blockIdx.y * 64 + lane;

    const float4* __restrict__ hrow =
        reinterpret_cast<const float4*>(hs + (size_t)row * H_DIM);

    // Wave-uniform W row pointers (SGPR-resident after readfirstlane on c0).
    const float4* wr[8];
    #pragma unroll
    for (int j = 0; j < 8; ++j) {
        const int c    = c0 + j;
        const int half = (c >= C_DIM) ? 1 : 0;
        const int ci   = c - half * C_DIM;
        wr[j] = reinterpret_cast<const float4*>(W + (size_t)ci * TWO_H
                                                  + (size_t)half * H_DIM);
    }

    float acc[8] = {0.f, 0.f, 0.f, 0.f, 0.f, 0.f, 0.f, 0.f};

    #pragma unroll 4
    for (int k = 0; k < H_DIM / 4; ++k) {
        const float4 h = hrow[k];
        #pragma unroll
        for (int j = 0; j < 8; ++j) {
            const float4 w = wr[j][k];     // uniform -> s_load_dwordx4
            acc[j] += h.x * w.x;
            acc[j] += h.y * w.y;
            acc[j] += h.z * w.z;
            acc[j] += h.w * w.w;
        }
    }

    #pragma unroll
    for (int j = 0; j < 8; ++j) {
        const int c    = c0 + j;
        const int half = (c >= C_DIM) ? 1 : 0;
        const int ci   = c - half * C_DIM;
        proj[(size_t)half * (NROWS * C_DIM) + (size_t)row * C_DIM + ci] = acc[j];
    }
}

// ---------------------------------------------------------------------------
// Kernel 2: out[b,i,j,c] = proj_i[b,i,c] + proj_j[b,j,c] + bias[c]
// grid = 2048 (one block per (b,i)), block = 256.
// In float4 units: out_slab[p] = projj_slab[p] + rowi[p % 12]
//   where slab = 512*48 floats = 6144 float4 (98 KB), fully linear.
// proj_j slab is L2-resident (98 KB/batch, reused by 512 blocks); the 201 MB
// output write stream is the roofline.
// ---------------------------------------------------------------------------
__global__ __launch_bounds__(256) void bcast_kernel(const float* __restrict__ proj,
                                                    const float* __restrict__ bias,
                                                    float* __restrict__ out) {
    const int gi = blockIdx.x;          // global row index = b*512 + i
    const int b  = gi >> 9;             // batch

    __shared__ float4 rowi[C_DIM / 4];  // proj_i[b,i,:] + bias  (12 float4)

    const int t = threadIdx.x;
    if (t < C_DIM / 4) {
        float4 pi = reinterpret_cast<const float4*>(proj + (size_t)gi * C_DIM)[t];
        float4 bb = reinterpret_cast<const float4*>(bias)[t];
        pi.x += bb.x; pi.y += bb.y; pi.z += bb.z; pi.w += bb.w;
        rowi[t] = pi;
    }
    __syncthreads();

    const float4* __restrict__ pj =
        reinterpret_cast<const float4*>(proj + (size_t)(NROWS * C_DIM)
                                             + (size_t)b * 512 * C_DIM);
    float4* __restrict__ o =
        reinterpret_cast<float4*>(out) + (size_t)gi * (512 * C_DIM / 4);

    constexpr int SLAB_F4 = 512 * C_DIM / 4;   // 6144
    #pragma unroll
    for (int it = 0; it < SLAB_F4 / 256; ++it) {
        const int p  = it * 256 + t;
        const int c4 = p % 12;
        float4 v  = pj[p];
        float4 si = rowi[c4];
        v.x += si.x; v.y += si.y; v.z += si.z; v.w += si.w;
        o[p] = v;
    }
}

extern "C" void kernel_launch(void* const* d_in, const int* in_sizes, int n_in,
                              void* d_out, int out_size, void* d_ws, size_t ws_size,
                              hipStream_t stream) {
    const float* hs   = (const float*)d_in[0];   // (4, 512, 768) f32
    const float* W    = (const float*)d_in[1];   // (48, 1536)    f32
    const float* bias = (const float*)d_in[2];   // (48,)         f32
    float* out  = (float*)d_out;                 // (4,512,512,48) f32
    float* proj = (float*)d_ws;                  // 2 * 2048 * 48 floats = 786 KB

    // Kernel 1: both projections into workspace (one wave per 8 columns).
    proj_kernel<<<dim3(12, 32), 64, 0, stream>>>(hs, W, proj);

    // Kernel 2: broadcast-add, one block per (b, i).
    bcast_kernel<<<dim3(NROWS), 256, 0, stream>>>(proj, bias, out);
}

// Round 4
// 58.057 us; speedup vs baseline: 2.1041x; 2.1041x over previous
//
#include <hip/hip_runtime.h>

typedef float f32x4 __attribute__((ext_vector_type(4)));

// Problem dims (fixed by reference): bs=4, L=512, H=768, C=48
#define H_DIM 768
#define C_DIM 48
#define NROWS 2048          // bs * L
#define TWO_H 1536

#define R_ROWS 8            // rows per proj block
#define KG     8            // k-groups per block
#define KSEG   (H_DIM / KG) // 96 k per group
#define CL     48           // col-lanes (each owns c and c+48)
#define WT_ELEMS (H_DIM * 96)   // 73728 floats

// ---------------------------------------------------------------------------
// Kernel 0: transpose W[48][1536] -> Wt[768][96] (k-major).
//   Wt[k][c] = W[c][k]        for c < 48   (i-half)
//   Wt[k][c] = W[c-48][768+k] for c >= 48  (j-half)
// 18432 threads, each moves 4 k's of one column (float4 read, 4 b32 writes).
// Wt lives in the tail of d_out (bcast overwrites it afterwards).
// ---------------------------------------------------------------------------
__global__ __launch_bounds__(256) void wtrans_kernel(const float* __restrict__ W,
                                                     float* __restrict__ Wt) {
    const int idx = blockIdx.x * 256 + threadIdx.x;   // 0..18431
    const int c   = idx % 96;
    const int k   = (idx / 96) * 4;                   // 0..764
    const float* src = W + (size_t)(c % C_DIM) * TWO_H + (c / C_DIM) * H_DIM + k;
    const float4 v = *reinterpret_cast<const float4*>(src);
    Wt[(size_t)(k + 0) * 96 + c] = v.x;
    Wt[(size_t)(k + 1) * 96 + c] = v.y;
    Wt[(size_t)(k + 2) * 96 + c] = v.z;
    Wt[(size_t)(k + 3) * 96 + c] = v.w;
}

// ---------------------------------------------------------------------------
// Kernel 1: proj[half][row][c] = dot(hs[row,:], W-col(half,c))
// grid = 256 blocks (8 rows each), block = 384 threads (6 waves).
// thread t: kg = t/48 (k-range [kg*96, kg*96+96)), cl = t%48 (cols cl, cl+48).
// hs rows in LDS, read as <=2-way-broadcast ds_read_b128 (conflict-free).
// Wt reads: lanes consecutive cl -> coalesced b32.
// 8-way k-partials merged through LDS at the end.
// ---------------------------------------------------------------------------
__global__ __launch_bounds__(384) void proj_kernel(const float* __restrict__ hs,
                                                   const float* __restrict__ Wt,
                                                   float* __restrict__ proj) {
    __shared__ float hs_lds[R_ROWS][H_DIM];       // 24 KB
    __shared__ float part[KG][CL][20];            // 16 used + 4 pad = 30 KB

    const int t    = threadIdx.x;
    const int kg   = t / CL;                      // 0..7
    const int cl   = t % CL;                      // 0..47
    const int row0 = blockIdx.x * R_ROWS;

    // Stage 8 hs rows into LDS (coalesced float4, 4 per thread).
    {
        const float4* src = reinterpret_cast<const float4*>(hs + (size_t)row0 * H_DIM);
        float4* dst = reinterpret_cast<float4*>(&hs_lds[0][0]);
        #pragma unroll
        for (int i = 0; i < 4; ++i) {
            const int p = i * 384 + t;            // 0..1535
            dst[p] = src[p];
        }
    }
    __syncthreads();

    float acc_i[R_ROWS], acc_j[R_ROWS];
    #pragma unroll
    for (int r = 0; r < R_ROWS; ++r) { acc_i[r] = 0.f; acc_j[r] = 0.f; }

    const int kbase = kg * KSEG;
    for (int kk = 0; kk < KSEG; kk += 4) {
        const int k = kbase + kk;
        float w0[4], w1[4];
        #pragma unroll
        for (int j = 0; j < 4; ++j) {
            w0[j] = Wt[(size_t)(k + j) * 96 + cl];        // i-half col
            w1[j] = Wt[(size_t)(k + j) * 96 + cl + 48];   // j-half col
        }
        #pragma unroll
        for (int r = 0; r < R_ROWS; ++r) {
            const float4 h = *reinterpret_cast<const float4*>(&hs_lds[r][k]);
            acc_i[r] += h.x * w0[0];  acc_i[r] += h.y * w0[1];
            acc_i[r] += h.z * w0[2];  acc_i[r] += h.w * w0[3];
            acc_j[r] += h.x * w1[0];  acc_j[r] += h.y * w1[1];
            acc_j[r] += h.z * w1[2];  acc_j[r] += h.w * w1[3];
        }
    }

    // Write k-partials to LDS and reduce across the 8 k-groups.
    #pragma unroll
    for (int r = 0; r < R_ROWS; ++r) {
        part[kg][cl][r * 2 + 0] = acc_i[r];
        part[kg][cl][r * 2 + 1] = acc_j[r];
    }
    __syncthreads();

    {
        const int rr = t / CL;                    // 0..7 (384 = 8*48 exactly)
        float pi = 0.f, pj = 0.f;
        #pragma unroll
        for (int g = 0; g < KG; ++g) {
            pi += part[g][cl][rr * 2 + 0];
            pj += part[g][cl][rr * 2 + 1];
        }
        proj[(size_t)(row0 + rr) * C_DIM + cl] = pi;
        proj[(size_t)NROWS * C_DIM + (size_t)(row0 + rr) * C_DIM + cl] = pj;
    }
}

// ---------------------------------------------------------------------------
// Kernel 2: out[b,i,j,c] = proj_i[b,i,c] + proj_j[b,j,c] + bias[c]
// grid = 2048 (one block per (b,i)), block = 256.
// proj_j slab (98 KB/batch) is L2-resident; nontemporal stores keep the
// 201 MB write stream from evicting it.
// ---------------------------------------------------------------------------
__global__ __launch_bounds__(256) void bcast_kernel(const float* __restrict__ proj,
                                                    const float* __restrict__ bias,
                                                    float* __restrict__ out) {
    const int gi = blockIdx.x;          // b*512 + i
    const int b  = gi >> 9;

    __shared__ f32x4 rowi[C_DIM / 4];   // proj_i[b,i,:] + bias  (12 float4)

    const int t = threadIdx.x;
    if (t < C_DIM / 4) {
        f32x4 pi = reinterpret_cast<const f32x4*>(proj + (size_t)gi * C_DIM)[t];
        f32x4 bb = reinterpret_cast<const f32x4*>(bias)[t];
        rowi[t] = pi + bb;
    }
    __syncthreads();

    const f32x4* __restrict__ pj =
        reinterpret_cast<const f32x4*>(proj + (size_t)NROWS * C_DIM
                                            + (size_t)b * 512 * C_DIM);
    f32x4* __restrict__ o =
        reinterpret_cast<f32x4*>(out) + (size_t)gi * (512 * C_DIM / 4);

    constexpr int SLAB_F4 = 512 * C_DIM / 4;   // 6144
    #pragma unroll
    for (int it = 0; it < SLAB_F4 / 256; ++it) {
        const int p  = it * 256 + t;
        const int c4 = p % 12;
        f32x4 v = pj[p] + rowi[c4];
        __builtin_nontemporal_store(v, &o[p]);
    }
}

extern "C" void kernel_launch(void* const* d_in, const int* in_sizes, int n_in,
                              void* d_out, int out_size, void* d_ws, size_t ws_size,
                              hipStream_t stream) {
    const float* hs   = (const float*)d_in[0];   // (4, 512, 768) f32
    const float* W    = (const float*)d_in[1];   // (48, 1536)    f32
    const float* bias = (const float*)d_in[2];   // (48,)         f32
    float* out  = (float*)d_out;                 // (4,512,512,48) f32
    float* proj = (float*)d_ws;                  // 2*2048*48 floats = 786 KB

    // Wt lives in the tail of d_out; proj reads it before bcast overwrites it.
    float* Wt = out + (size_t)out_size - WT_ELEMS;

    wtrans_kernel<<<dim3(WT_ELEMS / 4 / 256), 256, 0, stream>>>(W, Wt);
    proj_kernel<<<dim3(NROWS / R_ROWS), 384, 0, stream>>>(hs, Wt, proj);
    bcast_kernel<<<dim3(NROWS), 256, 0, stream>>>(proj, bias, out);
}